// Round 1
// baseline (609.308 us; speedup 1.0000x reference)
//
#include <hip/hip_runtime.h>
#include <stdint.h>

// ---------------------------------------------------------------------------
// AdjCompute: adj = |x[n]-x[m]| (64ch) -> 4x (1x1 conv + BN(train) + lrelu)
// -> 1x1 conv -> out[1536,1536].
// BN needs global per-channel stats of each layer's pre-activations -> 5
// sequential phases. Intermediates stored bf16 in ws (ping-pong).
//
// ws layout (floats unless noted):
//   [0..32)   stats1 (sum[16], sumsq[16])
//   [32..64)  stats2
//   [64..80)  stats3 (8+8)
//   [80..96)  stats4 (8+8)
//   [128..1152)  Wt1 [64][16]   (transposed W1)
//   [1152..1408) Wt2 [16][16]
//   [1408..1536) Wt3 [16][8]
//   [1536..1600) Wt4 [8][8]
//   byte 8192:              bufA  NN*16 bf16 = 75,497,472 B
//   byte 8192 + 75497472:   bufB  NN*16 bf16 = 75,497,472 B
// total ws needed = 151,003,136 B
// ---------------------------------------------------------------------------

#define NPTS 1536
#define NN   2359296u   // 1536*1536

static constexpr float EPS   = 1e-5f;
static constexpr float SLOPE = 0.01f;
static constexpr float INV_M = 1.0f / 2359296.0f;

__device__ __forceinline__ float bflo(unsigned u) {
    return __builtin_bit_cast(float, u << 16);
}
__device__ __forceinline__ float bfhi(unsigned u) {
    return __builtin_bit_cast(float, u & 0xffff0000u);
}
__device__ __forceinline__ unsigned short f2bf(float f) {
    unsigned u = __builtin_bit_cast(unsigned, f);
    u += 0x7fffu + ((u >> 16) & 1u);   // RNE
    return (unsigned short)(u >> 16);
}
__device__ __forceinline__ unsigned pack2(float lo, float hi) {
    return (unsigned)f2bf(lo) | ((unsigned)f2bf(hi) << 16);
}

// block-wide stats reduction: each thread holds sum[NCH], ssq[NCH];
// wave shuffle-reduce -> LDS -> one atomicAdd per block per value.
template <int NCH>
__device__ __forceinline__ void block_stats(float* sum, float* ssq,
                                            float* __restrict__ gstats) {
#pragma unroll
    for (int o = 0; o < NCH; o++) {
        float s = sum[o], q = ssq[o];
#pragma unroll
        for (int off = 32; off > 0; off >>= 1) {
            s += __shfl_down(s, off, 64);
            q += __shfl_down(q, off, 64);
        }
        sum[o] = s; ssq[o] = q;
    }
    __shared__ float red[4][2 * NCH];
    int wv = threadIdx.x >> 6, ln = threadIdx.x & 63;
    if (ln == 0) {
#pragma unroll
        for (int o = 0; o < NCH; o++) {
            red[wv][o]       = sum[o];
            red[wv][NCH + o] = ssq[o];
        }
    }
    __syncthreads();
    if (threadIdx.x < 2 * NCH) {
        float v = red[0][threadIdx.x] + red[1][threadIdx.x] +
                  red[2][threadIdx.x] + red[3][threadIdx.x];
        atomicAdd(gstats + threadIdx.x, v);
    }
}

// zero stats + transpose weights so inner loops read Wt[c*CO+o] (contiguous).
__global__ __launch_bounds__(256) void k_prep(
        const float* __restrict__ W1, const float* __restrict__ W2,
        const float* __restrict__ W3, const float* __restrict__ W4,
        float* __restrict__ ws) {
    int t = threadIdx.x;
    if (t < 96) ws[t] = 0.0f;
    for (int idx = t; idx < 1024; idx += 256) {     // W1 [16][64] -> [64][16]
        int o = idx >> 6, c = idx & 63;
        ws[128 + c * 16 + o] = W1[idx];
    }
    { int o = t >> 4, c = t & 15; ws[1152 + c * 16 + o] = W2[t]; }  // [16][16]
    if (t < 128) { int o = t >> 4, c = t & 15; ws[1408 + c * 8 + o] = W3[t]; }
    if (t < 64)  { int o = t >> 3, c = t & 7;  ws[1536 + c * 8 + o] = W4[t]; }
}

// Layer 1: h1_pre[n,m,o] = b1[o] + sum_c W1[o,c]*|x[n,c]-x[m,c]|
// block = 256 m's (x-row in VGPRs) x 8 n's (x-row wave-uniform -> s_load).
__global__ __launch_bounds__(256) void k_layer1(
        const float* __restrict__ x, const float* __restrict__ wt1,
        const float* __restrict__ b1, unsigned* __restrict__ outb,
        float* __restrict__ stats) {
    int bm = blockIdx.x % 6, bn = blockIdx.x / 6;
    int m = bm * 256 + threadIdx.x;

    float xm[64];
    const float4* xr = (const float4*)(x + m * 64);
#pragma unroll
    for (int q = 0; q < 16; q++) {
        float4 v = xr[q];
        xm[4*q] = v.x; xm[4*q+1] = v.y; xm[4*q+2] = v.z; xm[4*q+3] = v.w;
    }
    float sum[16], ssq[16];
#pragma unroll
    for (int o = 0; o < 16; o++) { sum[o] = 0.f; ssq[o] = 0.f; }

#pragma unroll 1
    for (int it = 0; it < 8; it++) {
        int n = bn * 8 + it;
        const float* xn = x + n * 64;   // wave-uniform address
        float acc[16];
#pragma unroll
        for (int o = 0; o < 16; o++) acc[o] = b1[o];
#pragma unroll
        for (int c = 0; c < 64; c++) {
            float t = fabsf(xm[c] - xn[c]);
#pragma unroll
            for (int o = 0; o < 16; o++)
                acc[o] = fmaf(t, wt1[c * 16 + o], acc[o]);
        }
#pragma unroll
        for (int o = 0; o < 16; o++) {
            sum[o] += acc[o];
            ssq[o] = fmaf(acc[o], acc[o], ssq[o]);
        }
        unsigned pk[8];
#pragma unroll
        for (int j = 0; j < 8; j++) pk[j] = pack2(acc[2*j], acc[2*j+1]);
        size_t p = (size_t)n * NPTS + m;
        uint4* dst = (uint4*)outb + p * 2;
        dst[0] = make_uint4(pk[0], pk[1], pk[2], pk[3]);
        dst[1] = make_uint4(pk[4], pk[5], pk[6], pk[7]);
    }
    block_stats<16>(sum, ssq, stats);
}

// Middle layers: read h_pre(bf16), BN+lrelu, matmul -> next h_pre(bf16)+stats
template <int CI, int CO>
__global__ __launch_bounds__(256) void k_mid(
        const uint4* __restrict__ inb, unsigned* __restrict__ outb,
        const float* __restrict__ statsIn, const float* __restrict__ g,
        const float* __restrict__ be, const float* __restrict__ wt,
        const float* __restrict__ b, float* __restrict__ statsOut) {
    float scale[CI], shift[CI];
#pragma unroll
    for (int c = 0; c < CI; c++) {
        float mu  = statsIn[c] * INV_M;
        float var = fmaf(-mu, mu, statsIn[CI + c] * INV_M);
        float inv = rsqrtf(var + EPS);
        float sc  = g[c] * inv;
        scale[c] = sc;
        shift[c] = fmaf(-mu, sc, be[c]);
    }
    float sum[CO], ssq[CO];
#pragma unroll
    for (int o = 0; o < CO; o++) { sum[o] = 0.f; ssq[o] = 0.f; }

    unsigned base = blockIdx.x * 2048u + threadIdx.x;
#pragma unroll 1
    for (int it = 0; it < 8; it++) {
        size_t p = base + (unsigned)it * 256u;
        float a[CI];
        const uint4* src = inb + p * (CI / 8);
#pragma unroll
        for (int q = 0; q < CI / 8; q++) {
            uint4 v = src[q];
            a[8*q+0] = bflo(v.x); a[8*q+1] = bfhi(v.x);
            a[8*q+2] = bflo(v.y); a[8*q+3] = bfhi(v.y);
            a[8*q+4] = bflo(v.z); a[8*q+5] = bfhi(v.z);
            a[8*q+6] = bflo(v.w); a[8*q+7] = bfhi(v.w);
        }
#pragma unroll
        for (int c = 0; c < CI; c++) {
            float t = fmaf(a[c], scale[c], shift[c]);
            a[c] = t > 0.f ? t : t * SLOPE;
        }
        float acc[CO];
#pragma unroll
        for (int o = 0; o < CO; o++) acc[o] = b[o];
#pragma unroll
        for (int c = 0; c < CI; c++) {
#pragma unroll
            for (int o = 0; o < CO; o++)
                acc[o] = fmaf(a[c], wt[c * CO + o], acc[o]);
        }
#pragma unroll
        for (int o = 0; o < CO; o++) {
            sum[o] += acc[o];
            ssq[o] = fmaf(acc[o], acc[o], ssq[o]);
        }
        unsigned pk[CO / 2];
#pragma unroll
        for (int j = 0; j < CO / 2; j++) pk[j] = pack2(acc[2*j], acc[2*j+1]);
        uint4* dst = (uint4*)outb + p * (CO / 8);
#pragma unroll
        for (int q = 0; q < CO / 8; q++)
            dst[q] = make_uint4(pk[4*q], pk[4*q+1], pk[4*q+2], pk[4*q+3]);
    }
    block_stats<CO>(sum, ssq, statsOut);
}

// Final layer: BN+lrelu on h4_pre then dot with W5[0,0:8] + b5 -> fp32 out
__global__ __launch_bounds__(256) void k_last(
        const uint4* __restrict__ inb, const float* __restrict__ stats,
        const float* __restrict__ g, const float* __restrict__ be,
        const float* __restrict__ W5, const float* __restrict__ b5,
        float* __restrict__ out) {
    float scale[8], shift[8];
#pragma unroll
    for (int c = 0; c < 8; c++) {
        float mu  = stats[c] * INV_M;
        float var = fmaf(-mu, mu, stats[8 + c] * INV_M);
        float inv = rsqrtf(var + EPS);
        float sc  = g[c] * inv;
        scale[c] = sc;
        shift[c] = fmaf(-mu, sc, be[c]);
    }
    unsigned p = blockIdx.x * 256u + threadIdx.x;
    uint4 v = inb[p];
    float a[8] = { bflo(v.x), bfhi(v.x), bflo(v.y), bfhi(v.y),
                   bflo(v.z), bfhi(v.z), bflo(v.w), bfhi(v.w) };
    float acc = b5[0];
#pragma unroll
    for (int c = 0; c < 8; c++) {
        float t = fmaf(a[c], scale[c], shift[c]);
        t = t > 0.f ? t : t * SLOPE;
        acc = fmaf(t, W5[c], acc);
    }
    out[p] = acc;
}

extern "C" void kernel_launch(void* const* d_in, const int* in_sizes, int n_in,
                              void* d_out, int out_size, void* d_ws,
                              size_t ws_size, hipStream_t stream) {
    const float* x   = (const float*)d_in[0];
    const float* W1  = (const float*)d_in[1];
    const float* b1  = (const float*)d_in[2];
    const float* g1  = (const float*)d_in[3];
    const float* be1 = (const float*)d_in[4];
    const float* W2  = (const float*)d_in[5];
    const float* b2  = (const float*)d_in[6];
    const float* g2  = (const float*)d_in[7];
    const float* be2 = (const float*)d_in[8];
    const float* W3  = (const float*)d_in[9];
    const float* b3  = (const float*)d_in[10];
    const float* g3  = (const float*)d_in[11];
    const float* be3 = (const float*)d_in[12];
    const float* W4  = (const float*)d_in[13];
    const float* b4  = (const float*)d_in[14];
    const float* g4  = (const float*)d_in[15];
    const float* be4 = (const float*)d_in[16];
    const float* W5  = (const float*)d_in[17];
    const float* b5  = (const float*)d_in[18];

    float* ws     = (float*)d_ws;
    float* stats1 = ws + 0;
    float* stats2 = ws + 32;
    float* stats3 = ws + 64;
    float* stats4 = ws + 80;
    float* wt1    = ws + 128;
    float* wt2    = ws + 1152;
    float* wt3    = ws + 1408;
    float* wt4    = ws + 1536;
    unsigned* bufA = (unsigned*)((char*)d_ws + 8192);
    unsigned* bufB = (unsigned*)((char*)d_ws + 8192 + (size_t)NN * 32u);

    k_prep<<<1, 256, 0, stream>>>(W1, W2, W3, W4, ws);
    k_layer1<<<1152, 256, 0, stream>>>(x, wt1, b1, bufA, stats1);
    k_mid<16, 16><<<1152, 256, 0, stream>>>((const uint4*)bufA, bufB,
                                            stats1, g1, be1, wt2, b2, stats2);
    k_mid<16, 8><<<1152, 256, 0, stream>>>((const uint4*)bufB, bufA,
                                           stats2, g2, be2, wt3, b3, stats3);
    k_mid<8, 8><<<1152, 256, 0, stream>>>((const uint4*)bufA, bufB,
                                          stats3, g3, be3, wt4, b4, stats4);
    k_last<<<9216, 256, 0, stream>>>((const uint4*)bufB, stats4, g4, be4,
                                     W5, b5, (float*)d_out);
}

// Round 2
// 274.134 us; speedup vs baseline: 2.2227x; 2.2227x over previous
//
#include <hip/hip_runtime.h>
#include <stdint.h>

// ---------------------------------------------------------------------------
// AdjCompute: adj = |x[n]-x[m]| (64ch) -> 4x (1x1 conv + BN(train) + lrelu)
// -> 1x1 conv -> out[1536,1536].
// BN needs global per-channel stats of each layer's pre-activations -> 5
// sequential phases. Intermediates stored bf16 in ws (ping-pong).
//
// R1: layer1 rewritten on MFMA (mfma_f32_16x16x32_bf16 x2, K=64).
//     A-fragments (adj tile) computed entirely in registers: lane holds
//     A[m=lane&15][k=quad*8+j] (+32 for 2nd mfma) -> 16 sub/abs/pack, no LDS.
//     B-fragments = bf16(W1) loaded once per wave. D init = bias.
//     C/D layout: col(o)=lane&15, row(m)=quad*4+reg  [guide §3, m89/m91].
//
// ws layout (floats unless noted):
//   [0..32)   stats1 (sum[16], sumsq[16])
//   [32..64)  stats2
//   [64..80)  stats3 (8+8)
//   [80..96)  stats4 (8+8)
//   [128..1152)  Wt1 [64][16]   (transposed W1; unused by MFMA path, kept)
//   [1152..1408) Wt2 [16][16]
//   [1408..1536) Wt3 [16][8]
//   [1536..1600) Wt4 [8][8]
//   byte 8192:              bufA  NN*16 bf16 = 75,497,472 B
//   byte 8192 + 75497472:   bufB  NN*16 bf16 = 75,497,472 B
// total ws needed = 151,003,136 B
// ---------------------------------------------------------------------------

#define NPTS 1536
#define NN   2359296u   // 1536*1536

static constexpr float EPS   = 1e-5f;
static constexpr float SLOPE = 0.01f;
static constexpr float INV_M = 1.0f / 2359296.0f;

typedef __attribute__((ext_vector_type(8))) short bf16x8;
typedef __attribute__((ext_vector_type(4))) float f32x4;
union frag8 { int4 i; bf16x8 v; };

__device__ __forceinline__ float bflo(unsigned u) {
    return __builtin_bit_cast(float, u << 16);
}
__device__ __forceinline__ float bfhi(unsigned u) {
    return __builtin_bit_cast(float, u & 0xffff0000u);
}
__device__ __forceinline__ unsigned short f2bf(float f) {
    unsigned u = __builtin_bit_cast(unsigned, f);
    u += 0x7fffu + ((u >> 16) & 1u);   // RNE
    return (unsigned short)(u >> 16);
}
__device__ __forceinline__ unsigned pack2(float lo, float hi) {
    return (unsigned)f2bf(lo) | ((unsigned)f2bf(hi) << 16);
}

// block-wide stats reduction: each thread holds sum[NCH], ssq[NCH];
// wave shuffle-reduce -> LDS -> one atomicAdd per block per value.
template <int NCH>
__device__ __forceinline__ void block_stats(float* sum, float* ssq,
                                            float* __restrict__ gstats) {
#pragma unroll
    for (int o = 0; o < NCH; o++) {
        float s = sum[o], q = ssq[o];
#pragma unroll
        for (int off = 32; off > 0; off >>= 1) {
            s += __shfl_down(s, off, 64);
            q += __shfl_down(q, off, 64);
        }
        sum[o] = s; ssq[o] = q;
    }
    __shared__ float red[4][2 * NCH];
    int wv = threadIdx.x >> 6, ln = threadIdx.x & 63;
    if (ln == 0) {
#pragma unroll
        for (int o = 0; o < NCH; o++) {
            red[wv][o]       = sum[o];
            red[wv][NCH + o] = ssq[o];
        }
    }
    __syncthreads();
    if (threadIdx.x < 2 * NCH) {
        float v = red[0][threadIdx.x] + red[1][threadIdx.x] +
                  red[2][threadIdx.x] + red[3][threadIdx.x];
        atomicAdd(gstats + threadIdx.x, v);
    }
}

// zero stats + transpose weights so inner loops read Wt[c*CO+o] (contiguous).
__global__ __launch_bounds__(256) void k_prep(
        const float* __restrict__ W1, const float* __restrict__ W2,
        const float* __restrict__ W3, const float* __restrict__ W4,
        float* __restrict__ ws) {
    int t = threadIdx.x;
    if (t < 96) ws[t] = 0.0f;
    for (int idx = t; idx < 1024; idx += 256) {     // W1 [16][64] -> [64][16]
        int o = idx >> 6, c = idx & 63;
        ws[128 + c * 16 + o] = W1[idx];
    }
    { int o = t >> 4, c = t & 15; ws[1152 + c * 16 + o] = W2[t]; }  // [16][16]
    if (t < 128) { int o = t >> 4, c = t & 15; ws[1408 + c * 8 + o] = W3[t]; }
    if (t < 64)  { int o = t >> 3, c = t & 7;  ws[1536 + c * 8 + o] = W4[t]; }
}

// Layer 1 (MFMA): h1[n, m, o] = b1[o] + sum_c W1[o,c] * |x[m,c]-x[n,c]|
// wave unit = 16 m's x 16 o's x 1 n; wave loop = 48 n's.
// grid: 3072 waves = 96 m-tiles x 32 n-chunks.
__global__ __launch_bounds__(256) void k_layer1(
        const float* __restrict__ x, const float* __restrict__ W1,
        const float* __restrict__ b1, unsigned short* __restrict__ outb,
        float* __restrict__ stats) {
    int lane = threadIdx.x & 63;
    int wv   = threadIdx.x >> 6;
    int gid  = blockIdx.x * 4 + wv;
    int mt   = gid % 96;          // m-tile
    int nc   = gid / 96;          // n-chunk 0..31
    int o    = lane & 15;
    int quad = lane >> 4;
    int cb   = quad * 8;          // k-base for this lane's fragments

    // B fragments: B[k=cb+j][o] = W1[o][cb+j]  (and +32 for 2nd mfma)
    const float* wr = W1 + o * 64 + cb;
    float4 w0 = *(const float4*)(wr);
    float4 w1 = *(const float4*)(wr + 4);
    float4 w2 = *(const float4*)(wr + 32);
    float4 w3 = *(const float4*)(wr + 36);
    frag8 fb1, fb2;
    fb1.i = make_int4(pack2(w0.x, w0.y), pack2(w0.z, w0.w),
                      pack2(w1.x, w1.y), pack2(w1.z, w1.w));
    fb2.i = make_int4(pack2(w2.x, w2.y), pack2(w2.z, w2.w),
                      pack2(w3.x, w3.y), pack2(w3.z, w3.w));

    // xm for this lane's A-rows: x[mt*16 + (lane&15)][cb..cb+7, 32+cb..]
    const float* xr = x + (mt * 16 + o) * 64 + cb;
    float4 xa0 = *(const float4*)(xr);
    float4 xa1 = *(const float4*)(xr + 4);
    float4 xa2 = *(const float4*)(xr + 32);
    float4 xa3 = *(const float4*)(xr + 36);

    float bias = b1[o];
    float lsum = 0.f, lssq = 0.f;
    unsigned mrow = mt * 16 + quad * 4;   // D rows this lane stores

#pragma unroll 1
    for (int i = 0; i < 48; i++) {
        int n = nc * 48 + i;
        const float* xn = x + n * 64 + cb;     // uniform within a quad
        float4 u0 = *(const float4*)(xn);
        float4 u1 = *(const float4*)(xn + 4);
        float4 u2 = *(const float4*)(xn + 32);
        float4 u3 = *(const float4*)(xn + 36);
        frag8 fa1, fa2;
        fa1.i = make_int4(
            pack2(fabsf(xa0.x - u0.x), fabsf(xa0.y - u0.y)),
            pack2(fabsf(xa0.z - u0.z), fabsf(xa0.w - u0.w)),
            pack2(fabsf(xa1.x - u1.x), fabsf(xa1.y - u1.y)),
            pack2(fabsf(xa1.z - u1.z), fabsf(xa1.w - u1.w)));
        fa2.i = make_int4(
            pack2(fabsf(xa2.x - u2.x), fabsf(xa2.y - u2.y)),
            pack2(fabsf(xa2.z - u2.z), fabsf(xa2.w - u2.w)),
            pack2(fabsf(xa3.x - u3.x), fabsf(xa3.y - u3.y)),
            pack2(fabsf(xa3.z - u3.z), fabsf(xa3.w - u3.w)));
        f32x4 acc = {bias, bias, bias, bias};
        acc = __builtin_amdgcn_mfma_f32_16x16x32_bf16(fa1.v, fb1.v, acc, 0, 0, 0);
        acc = __builtin_amdgcn_mfma_f32_16x16x32_bf16(fa2.v, fb2.v, acc, 0, 0, 0);

        size_t base = ((size_t)n * NPTS + mrow) * 16 + o;
#pragma unroll
        for (int r = 0; r < 4; r++) {
            float v = acc[r];
            lsum += v;
            lssq = fmaf(v, v, lssq);
            outb[base + (unsigned)r * 16u] = f2bf(v);
        }
    }
    // reduce over lanes sharing o (lane, lane^16, lane^32, lane^48)
    lsum += __shfl_xor(lsum, 16); lssq += __shfl_xor(lssq, 16);
    lsum += __shfl_xor(lsum, 32); lssq += __shfl_xor(lssq, 32);
    if (quad == 0) {
        atomicAdd(stats + o, lsum);
        atomicAdd(stats + 16 + o, lssq);
    }
}

// Middle layers: read h_pre(bf16), BN+lrelu, matmul -> next h_pre(bf16)+stats
template <int CI, int CO>
__global__ __launch_bounds__(256) void k_mid(
        const uint4* __restrict__ inb, unsigned* __restrict__ outb,
        const float* __restrict__ statsIn, const float* __restrict__ g,
        const float* __restrict__ be, const float* __restrict__ wt,
        const float* __restrict__ b, float* __restrict__ statsOut) {
    float scale[CI], shift[CI];
#pragma unroll
    for (int c = 0; c < CI; c++) {
        float mu  = statsIn[c] * INV_M;
        float var = fmaf(-mu, mu, statsIn[CI + c] * INV_M);
        float inv = rsqrtf(var + EPS);
        float sc  = g[c] * inv;
        scale[c] = sc;
        shift[c] = fmaf(-mu, sc, be[c]);
    }
    float sum[CO], ssq[CO];
#pragma unroll
    for (int o = 0; o < CO; o++) { sum[o] = 0.f; ssq[o] = 0.f; }

    unsigned base = blockIdx.x * 2048u + threadIdx.x;
#pragma unroll 1
    for (int it = 0; it < 8; it++) {
        size_t p = base + (unsigned)it * 256u;
        float a[CI];
        const uint4* src = inb + p * (CI / 8);
#pragma unroll
        for (int q = 0; q < CI / 8; q++) {
            uint4 v = src[q];
            a[8*q+0] = bflo(v.x); a[8*q+1] = bfhi(v.x);
            a[8*q+2] = bflo(v.y); a[8*q+3] = bfhi(v.y);
            a[8*q+4] = bflo(v.z); a[8*q+5] = bfhi(v.z);
            a[8*q+6] = bflo(v.w); a[8*q+7] = bfhi(v.w);
        }
#pragma unroll
        for (int c = 0; c < CI; c++) {
            float t = fmaf(a[c], scale[c], shift[c]);
            a[c] = t > 0.f ? t : t * SLOPE;
        }
        float acc[CO];
#pragma unroll
        for (int o = 0; o < CO; o++) acc[o] = b[o];
#pragma unroll
        for (int c = 0; c < CI; c++) {
#pragma unroll
            for (int o = 0; o < CO; o++)
                acc[o] = fmaf(a[c], wt[c * CO + o], acc[o]);
        }
#pragma unroll
        for (int o = 0; o < CO; o++) {
            sum[o] += acc[o];
            ssq[o] = fmaf(acc[o], acc[o], ssq[o]);
        }
        unsigned pk[CO / 2];
#pragma unroll
        for (int j = 0; j < CO / 2; j++) pk[j] = pack2(acc[2*j], acc[2*j+1]);
        uint4* dst = (uint4*)outb + p * (CO / 8);
#pragma unroll
        for (int q = 0; q < CO / 8; q++)
            dst[q] = make_uint4(pk[4*q], pk[4*q+1], pk[4*q+2], pk[4*q+3]);
    }
    block_stats<CO>(sum, ssq, statsOut);
}

// Final layer: BN+lrelu on h4_pre then dot with W5[0,0:8] + b5 -> fp32 out
__global__ __launch_bounds__(256) void k_last(
        const uint4* __restrict__ inb, const float* __restrict__ stats,
        const float* __restrict__ g, const float* __restrict__ be,
        const float* __restrict__ W5, const float* __restrict__ b5,
        float* __restrict__ out) {
    float scale[8], shift[8];
#pragma unroll
    for (int c = 0; c < 8; c++) {
        float mu  = stats[c] * INV_M;
        float var = fmaf(-mu, mu, stats[8 + c] * INV_M);
        float inv = rsqrtf(var + EPS);
        float sc  = g[c] * inv;
        scale[c] = sc;
        shift[c] = fmaf(-mu, sc, be[c]);
    }
    unsigned p = blockIdx.x * 256u + threadIdx.x;
    uint4 v = inb[p];
    float a[8] = { bflo(v.x), bfhi(v.x), bflo(v.y), bfhi(v.y),
                   bflo(v.z), bfhi(v.z), bflo(v.w), bfhi(v.w) };
    float acc = b5[0];
#pragma unroll
    for (int c = 0; c < 8; c++) {
        float t = fmaf(a[c], scale[c], shift[c]);
        t = t > 0.f ? t : t * SLOPE;
        acc = fmaf(t, W5[c], acc);
    }
    out[p] = acc;
}

extern "C" void kernel_launch(void* const* d_in, const int* in_sizes, int n_in,
                              void* d_out, int out_size, void* d_ws,
                              size_t ws_size, hipStream_t stream) {
    const float* x   = (const float*)d_in[0];
    const float* W1  = (const float*)d_in[1];
    const float* b1  = (const float*)d_in[2];
    const float* g1  = (const float*)d_in[3];
    const float* be1 = (const float*)d_in[4];
    const float* W2  = (const float*)d_in[5];
    const float* b2  = (const float*)d_in[6];
    const float* g2  = (const float*)d_in[7];
    const float* be2 = (const float*)d_in[8];
    const float* W3  = (const float*)d_in[9];
    const float* b3  = (const float*)d_in[10];
    const float* g3  = (const float*)d_in[11];
    const float* be3 = (const float*)d_in[12];
    const float* W4  = (const float*)d_in[13];
    const float* b4  = (const float*)d_in[14];
    const float* g4  = (const float*)d_in[15];
    const float* be4 = (const float*)d_in[16];
    const float* W5  = (const float*)d_in[17];
    const float* b5  = (const float*)d_in[18];

    float* ws     = (float*)d_ws;
    float* stats1 = ws + 0;
    float* stats2 = ws + 32;
    float* stats3 = ws + 64;
    float* stats4 = ws + 80;
    float* wt2    = ws + 1152;
    float* wt3    = ws + 1408;
    float* wt4    = ws + 1536;
    unsigned* bufA = (unsigned*)((char*)d_ws + 8192);
    unsigned* bufB = (unsigned*)((char*)d_ws + 8192 + (size_t)NN * 32u);

    k_prep<<<1, 256, 0, stream>>>(W1, W2, W3, W4, ws);
    k_layer1<<<768, 256, 0, stream>>>(x, W1, b1, (unsigned short*)bufA, stats1);
    k_mid<16, 16><<<1152, 256, 0, stream>>>((const uint4*)bufA, bufB,
                                            stats1, g1, be1, wt2, b2, stats2);
    k_mid<16, 8><<<1152, 256, 0, stream>>>((const uint4*)bufB, bufA,
                                           stats2, g2, be2, wt3, b3, stats3);
    k_mid<8, 8><<<1152, 256, 0, stream>>>((const uint4*)bufA, bufB,
                                          stats3, g3, be3, wt4, b4, stats4);
    k_last<<<9216, 256, 0, stream>>>((const uint4*)bufB, stats4, g4, be4,
                                     W5, b5, (float*)d_out);
}